// Round 2
// baseline (2474.230 us; speedup 1.0000x reference)
//
#include <hip/hip_runtime.h>

// ---------------- problem constants ----------------
#define BB    128
#define BUFF  64
#define STK   48
#define NCOMP 8
#define HIST  96
#define WDIM  300
#define POSD  50
#define CAD   50
#define HAD   50
#define FC    128
#define UU    256
#define NOUT  82

typedef __bf16 bf16;
typedef __attribute__((ext_vector_type(8))) __bf16 bf16x8;
typedef __attribute__((ext_vector_type(4))) float   f32x4;

__device__ __forceinline__ float sigf(float x)   { return 1.f / (1.f + __expf(-x)); }
__device__ __forceinline__ float tanhf_(float x) { return 1.f - 2.f / (1.f + __expf(2.f * x)); }

// pack two consecutive fp32 values as two bf16 in one u32
__device__ __forceinline__ unsigned pack2(const float* p) {
  union { unsigned u; bf16 h[2]; } r;
  r.h[0] = (bf16)p[0]; r.h[1] = (bf16)p[1];
  return r.u;
}

__device__ __forceinline__ bf16x8 aload16(const bf16* p) {
  union { unsigned long long q[2]; bf16x8 v; } u;
  u.q[0] = __hip_atomic_load((const unsigned long long*)p,       __ATOMIC_RELAXED, __HIP_MEMORY_SCOPE_AGENT);
  u.q[1] = __hip_atomic_load((const unsigned long long*)(p + 4), __ATOMIC_RELAXED, __HIP_MEMORY_SCOPE_AGENT);
  return u.v;
}

// =====================================================================
// Kernel 1: embedding MLP.  rows 0..98303 = comp, 98304..106495 = buff.
// out = relu(concat(w_emb[word](300), p_emb[pos](50)) @ emb_W(350x128) + b)
// =====================================================================
__global__ __launch_bounds__(256) void k_emb(
    const int* bw, const int* bp, const int* cw, const int* cp,
    const float* w_emb, const float* p_emb, const float* embW, const float* embB,
    bf16* comp_emb, bf16* buff_emb)
{
  __shared__ __align__(16) char sm[138752];
  bf16*  A  = (bf16*)sm;                    // [64][360]
  bf16*  Wt = (bf16*)(sm + 46080);          // [128][360] (transposed: [n][k])
  float* sb = (float*)(sm + 46080 + 92160); // [128]

  const int tid = threadIdx.x;
  const int r0  = blockIdx.x * 64;

  // stage A rows (word||pos||0), converting fp32 -> bf16, 2 per u32
  for (int i = tid; i < 64 * 176; i += 256) {
    int m = i / 176, c2 = i % 176, e0 = 2 * c2;
    int r = r0 + m;
    unsigned v;
    if (e0 < 300) {
      int word = (r < 98304) ? cw[r] : bw[r - 98304];
      v = pack2(w_emb + word * 300 + e0);
    } else if (e0 < 350) {
      int pos = (r < 98304) ? cp[r] : bp[r - 98304];
      v = pack2(p_emb + pos * 50 + (e0 - 300));
    } else v = 0u;
    *(unsigned*)(A + m * 360 + e0) = v;
  }
  // stage W transposed (fp32 -> bf16)
  for (int i = tid; i < 350 * 128; i += 256) {
    int k = i >> 7, n = i & 127;
    Wt[n * 360 + k] = (bf16)embW[i];
  }
  // zero k=350,351 in Wt
  { int i = tid; if (i < 256) { int n = i >> 1; Wt[n * 360 + 350 + (i & 1)] = (bf16)0.f; } }
  if (tid < 128) sb[tid] = embB[tid];
  __syncthreads();

  const int wv = tid >> 6, lane = tid & 63, l15 = lane & 15, quad = lane >> 4;
  f32x4 acc[8];
#pragma unroll
  for (int i = 0; i < 8; ++i) acc[i] = (f32x4){0.f, 0.f, 0.f, 0.f};

  const bf16* Arow = A + (wv * 16 + l15) * 360;
  for (int ks = 0; ks < 11; ++ks) {
    int kq = ks * 32 + quad * 8;
    bf16x8 a = *(const bf16x8*)(Arow + kq);
#pragma unroll
    for (int nt = 0; nt < 8; ++nt) {
      bf16x8 b = *(const bf16x8*)(Wt + (nt * 16 + l15) * 360 + kq);
      acc[nt] = __builtin_amdgcn_mfma_f32_16x16x32_bf16(a, b, acc[nt], 0, 0, 0);
    }
  }
#pragma unroll
  for (int nt = 0; nt < 8; ++nt)
#pragma unroll
    for (int rr = 0; rr < 4; ++rr) {
      int row = wv * 16 + quad * 4 + rr;
      int n   = nt * 16 + l15;
      float z = fmaxf(acc[nt][rr] + sb[n], 0.f);
      int r = r0 + row;
      bf16 o = (bf16)z;
      if (r < 98304) comp_emb[r * 128 + n] = o;
      else           buff_emb[(r - 98304) * 128 + n] = o;
    }
}

// =====================================================================
// Kernel 2: compose.  16 (b,s) pairs per block, 8 sequential steps in LDS.
// =====================================================================
__global__ __launch_bounds__(256) void k_compose(
    const int* cw, const int* caid, const int* calen,
    const bf16* comp_emb, const float* ca_emb, const float* recW, const float* recB,
    bf16* stack_emb)
{
  __shared__ __align__(16) char sm[129344];
  bf16*  Wt   = (bf16*)sm;              // [128][328]
  bf16*  X    = (bf16*)(sm + 83968);    // [16][328]
  bf16*  VALS = (bf16*)(sm + 94464);    // [16][8][128]
  float* recb = (float*)(sm + 127232);  // [128]
  int*   IH   = (int*)(sm + 127744);    // [16][8]
  int*   ID   = (int*)(sm + 128256);
  int*   AN   = (int*)(sm + 128768);
  int*   ALEN = (int*)(sm + 129280);    // [16]

  const int tid = threadIdx.x;
  const int bs0 = blockIdx.x * 16;

  for (int i = tid; i < 306 * 128; i += 256) {
    int k = i >> 7, n = i & 127;
    Wt[n * 328 + k] = (bf16)recW[i];
  }
  for (int i = tid; i < 128 * 22; i += 256) {  // zero pad rows 306..327
    int n = i / 22, k = 306 + i % 22;
    Wt[n * 328 + k] = (bf16)0.f;
  }
  if (tid < 128) recb[tid] = recB[tid];
  if (tid < 16) {
    int bs = bs0 + tid;
    int hid[8], did[8];
#pragma unroll
    for (int m = 0; m < 8; ++m) { hid[m] = cw[bs * 16 + 2 * m]; did[m] = cw[bs * 16 + 2 * m + 1]; }
    for (int n = 0; n < 8; ++n) {
      int ih = -1, idd = -1;
      for (int m = 0; m < n; ++m) { if (hid[m] == hid[n]) ih = m; if (hid[m] == did[n]) idd = m; }
      IH[tid * 8 + n] = ih; ID[tid * 8 + n] = idd; AN[tid * 8 + n] = caid[bs * 8 + n];
    }
    ALEN[tid] = calen[bs];
  }
  __syncthreads();

  const int wv = tid >> 6, lane = tid & 63, l15 = lane & 15, quad = lane >> 4;

  for (int n = 0; n < 8; ++n) {
    // stage X = [head_e(128) | act(50) | dep_e(128) | 0 pad] per pair
    for (int i = tid; i < 16 * 160; i += 256) {
      int p = i / 160, c2 = i % 160, e0 = 2 * c2;
      int bs = bs0 + p;
      unsigned v;
      if (e0 < 128) {
        int ih = IH[p * 8 + n];
        v = (ih >= 0) ? *(const unsigned*)(VALS + (p * 8 + ih) * 128 + e0)
                      : *(const unsigned*)(comp_emb + (bs * 16 + 2 * n) * 128 + e0);
      } else if (e0 < 178) {
        v = pack2(ca_emb + AN[p * 8 + n] * 50 + (e0 - 128));
      } else if (e0 < 306) {
        int e = e0 - 178;
        int idd = ID[p * 8 + n];
        v = (idd >= 0) ? *(const unsigned*)(VALS + (p * 8 + idd) * 128 + e)
                       : *(const unsigned*)(comp_emb + (bs * 16 + 2 * n + 1) * 128 + e);
      } else v = 0u;
      *(unsigned*)(X + p * 328 + e0) = v;
    }
    __syncthreads();

    f32x4 acc[2];
    acc[0] = (f32x4){0.f,0.f,0.f,0.f}; acc[1] = (f32x4){0.f,0.f,0.f,0.f};
    for (int ks = 0; ks < 10; ++ks) {
      int kq = ks * 32 + quad * 8;
      bf16x8 a = *(const bf16x8*)(X + l15 * 328 + kq);
#pragma unroll
      for (int t2 = 0; t2 < 2; ++t2) {
        int nt = 2 * wv + t2;
        bf16x8 b = *(const bf16x8*)(Wt + (nt * 16 + l15) * 328 + kq);
        acc[t2] = __builtin_amdgcn_mfma_f32_16x16x32_bf16(a, b, acc[t2], 0, 0, 0);
      }
    }
    __syncthreads();
#pragma unroll
    for (int t2 = 0; t2 < 2; ++t2) {
      int nt = 2 * wv + t2;
#pragma unroll
      for (int rr = 0; rr < 4; ++rr) {
        int p = quad * 4 + rr;
        int col = nt * 16 + l15;
        VALS[(p * 8 + n) * 128 + col] = (bf16)tanhf_(acc[t2][rr] + recb[col]);
      }
    }
    __syncthreads();
  }

  for (int i = tid; i < 16 * 64; i += 256) {
    int p = i / 64, c2 = i % 64, e0 = 2 * c2;
    int bs = bs0 + p;
    int al = ALEN[p];
    unsigned v = (al == 0) ? *(const unsigned*)(comp_emb + (bs * 16) * 128 + e0)
                           : *(const unsigned*)(VALS + (p * 8 + (al - 1)) * 128 + e0);
    *(unsigned*)(stack_emb + bs * 128 + e0) = v;
  }
}

// =====================================================================
// Kernel 3: persistent 3x 2-layer masked LSTM.
// 48 blocks: L = bx/16; within: layer = (bx%16)/8, uchunk = bx%8
// (32 u-columns of all 4 gates).  Phase p: L0 computes step p, L1 computes
// step p-1 (skewed) -> one inter-block barrier per phase.
// =====================================================================
struct BarT { int cnt; int gen; int pad[30]; };

__global__ __launch_bounds__(256) void k_lstm(
    const float* sW0, const float* sb0, const float* sW1, const float* sb1,
    const float* bW0, const float* bb0, const float* bW1, const float* bb1,
    const float* aW0, const float* ab0, const float* aW1, const float* ab1,
    const bf16* stack_emb, const bf16* buff_emb, const float* hist_tab, const int* hist_id,
    const int* len_s, const int* len_b, const int* len_a,
    bf16* h0buf, bf16* h1buf, BarT* bars)
{
  __shared__ __align__(16) char sm[143872];
  const int tid = threadIdx.x;
  const int bx  = blockIdx.x;
  const int L     = bx >> 4;
  const int rid   = bx & 15;
  const int layer = rid >> 3;
  const int u0    = (rid & 7) * 32;
  const int T     = (L == 0) ? STK : (L == 1) ? BUFF : HIST;
  const int* lenp = (L == 0) ? len_s : (L == 1) ? len_b : len_a;

  const float *W, *bias;
  int K, KP, Kxp;
  if (layer == 0) {
    W = (L == 0) ? sW0 : (L == 1) ? bW0 : aW0;
    bias = (L == 0) ? sb0 : (L == 1) ? bb0 : ab0;
    if (L == 2) { K = 320; KP = 328; Kxp = 64; } else { K = 384; KP = 392; Kxp = 128; }
  } else {
    W = (L == 0) ? sW1 : (L == 1) ? bW1 : aW1;
    bias = (L == 0) ? sb1 : (L == 1) ? bb1 : ab1;
    K = 512; KP = 520; Kxp = 256;
  }
  bf16*  Wt     = (bf16*)sm;                               // [128][KP]
  bf16*  hstage = (bf16*)(sm + 128 * KP * 2);              // [128][36]
  float* sb     = (float*)(sm + 128 * KP * 2 + 9216);      // [128]
  bf16*  Xa     = (bf16*)(sm + 128 * KP * 2 + 9216 + 512); // [128][72] (action L0)

  // stage weight slice, transposed: Wt[cc][kk], cc = gate*32 + within
  for (int i = tid; i < K * 128; i += 256) {
    int kk = i >> 7, cc = i & 127;
    int col = (cc >> 5) * 256 + u0 + (cc & 31);
    bf16 v;
    if (layer == 0 && L == 2) {
      if (kk < 64) v = (kk < 50) ? (bf16)W[kk * 1024 + col] : (bf16)0.f;
      else         v = (bf16)W[(kk - 14) * 1024 + col];
    } else v = (bf16)W[kk * 1024 + col];
    Wt[cc * KP + kk] = v;
  }
  if (tid < 128) { int col = (tid >> 5) * 256 + u0 + (tid & 31); sb[tid] = bias[col]; }

  const int wv = tid >> 6, lane = tid & 63, l15 = lane & 15, quad = lane >> 4;
  int lenr[8];
#pragma unroll
  for (int mt = 0; mt < 2; ++mt)
#pragma unroll
    for (int rr = 0; rr < 4; ++rr)
      lenr[mt * 4 + rr] = lenp[32 * wv + 16 * mt + quad * 4 + rr];

  float cst[16], hst[16];
#pragma unroll
  for (int i = 0; i < 16; ++i) { cst[i] = 0.f; hst[i] = 0.f; }

  BarT* bar = bars + L;
  bf16* h0w = h0buf + L * 2 * 32768;  // [2][128][256]
  bf16* h1w = h1buf + L * 2 * 32768;
  const bf16* xsrc = (L == 0) ? stack_emb : buff_emb;
  const int Tx = (L == 0) ? STK : BUFF;

  __syncthreads();

  for (int p = 0; p <= T; ++p) {
    const bool active = (layer == 0) ? (p < T) : (p >= 1);
    const int  t = (layer == 0) ? p : (p - 1);

    if (L == 2 && layer == 0 && active) {  // stage action x_t (50 -> 64 padded)
      for (int i = tid; i < 128 * 32; i += 256) {
        int row = i >> 5, e0 = 2 * (i & 31);
        unsigned v = 0u;
        if (e0 < 50) { int id = hist_id[row * 96 + t]; v = pack2(hist_tab + id * 50 + e0); }
        *(unsigned*)(Xa + row * 72 + e0) = v;
      }
    }
    __syncthreads();

    if (active) {
      f32x4 acc[2][8];
#pragma unroll
      for (int a1 = 0; a1 < 2; ++a1)
#pragma unroll
        for (int a2 = 0; a2 < 8; ++a2) acc[a1][a2] = (f32x4){0.f, 0.f, 0.f, 0.f};

      const bf16* h0r = h0w + ((p - 1) & 1) * 32768;
      const bf16* h1r = h1w + (p & 1) * 32768;

      for (int ks = 0; ks < K / 32; ++ks) {
        int k0 = ks * 32;
        int kq = k0 + quad * 8;
        bf16x8 a[2];
#pragma unroll
        for (int mt = 0; mt < 2; ++mt) {
          int row = 32 * wv + 16 * mt + l15;
          if (layer == 0) {
            if (k0 < Kxp) {
              if (L == 2) a[mt] = *(const bf16x8*)(Xa + row * 72 + kq);
              else        a[mt] = *(const bf16x8*)(xsrc + (row * Tx + t) * 128 + kq);
            } else a[mt] = aload16(h0r + row * 256 + (kq - Kxp));
          } else {
            if (k0 < 256) a[mt] = aload16(h0r + row * 256 + kq);
            else          a[mt] = aload16(h1r + row * 256 + (kq - 256));
          }
        }
#pragma unroll
        for (int nt = 0; nt < 8; ++nt) {
          bf16x8 b = *(const bf16x8*)(Wt + (nt * 16 + l15) * KP + kq);
          acc[0][nt] = __builtin_amdgcn_mfma_f32_16x16x32_bf16(a[0], b, acc[0][nt], 0, 0, 0);
          acc[1][nt] = __builtin_amdgcn_mfma_f32_16x16x32_bf16(a[1], b, acc[1][nt], 0, 0, 0);
        }
      }
      // gates: nt 0,1 = i ; 2,3 = j ; 4,5 = f ; 6,7 = o
#pragma unroll
      for (int mt = 0; mt < 2; ++mt)
#pragma unroll
        for (int g2 = 0; g2 < 2; ++g2)
#pragma unroll
          for (int rr = 0; rr < 4; ++rr) {
            int row = 32 * wv + 16 * mt + quad * 4 + rr;
            float zi = acc[mt][0 + g2][rr] + sb[(0 + g2) * 16 + l15];
            float zj = acc[mt][2 + g2][rr] + sb[(2 + g2) * 16 + l15];
            float zf = acc[mt][4 + g2][rr] + sb[(4 + g2) * 16 + l15];
            float zo = acc[mt][6 + g2][rr] + sb[(6 + g2) * 16 + l15];
            float ig = sigf(zi), jg = tanhf_(zj), fg = sigf(zf + 1.f), og = sigf(zo);
            int idx = mt * 8 + g2 * 4 + rr;
            float cn = cst[idx] * fg + ig * jg;
            float hn = tanhf_(cn) * og;
            bool mk = (t < lenr[mt * 4 + rr]);
            cst[idx] = mk ? cn : cst[idx];
            hst[idx] = mk ? hn : hst[idx];
            hstage[row * 36 + g2 * 16 + l15] = (bf16)hst[idx];
          }
    }
    __syncthreads();
    if (active) {
      bf16* dst = (layer == 0) ? (h0w + (p & 1) * 32768) : (h1w + ((p - 1) & 1) * 32768);
      for (int i = tid; i < 128 * 8; i += 256) {
        int row = i >> 3, c = i & 7;
        unsigned long long v = *(const unsigned long long*)(hstage + row * 36 + c * 4);
        __hip_atomic_store((unsigned long long*)(dst + row * 256 + u0 + c * 4), v,
                           __ATOMIC_RELAXED, __HIP_MEMORY_SCOPE_AGENT);
      }
    }
    // inter-block barrier (16 participants, per-LSTM)
    __threadfence();
    __syncthreads();
    if (tid == 0) {
      int prev = __hip_atomic_fetch_add(&bar->cnt, 1, __ATOMIC_ACQ_REL, __HIP_MEMORY_SCOPE_AGENT);
      if (prev == 15) {
        __hip_atomic_store(&bar->cnt, 0, __ATOMIC_RELAXED, __HIP_MEMORY_SCOPE_AGENT);
        __hip_atomic_fetch_add(&bar->gen, 1, __ATOMIC_RELEASE, __HIP_MEMORY_SCOPE_AGENT);
      } else {
        while (__hip_atomic_load(&bar->gen, __ATOMIC_ACQUIRE, __HIP_MEMORY_SCOPE_AGENT) <= p)
          __builtin_amdgcn_s_sleep(1);
      }
    }
    __syncthreads();
  }
}

// =====================================================================
// Kernel 4: out = concat(h_s,h_b,h_a) @ fW + fb
// =====================================================================
__global__ __launch_bounds__(128) void k_final(
    const bf16* h1buf, const float* fW, const float* fb, float* out)
{
  __shared__ float hs[768];
  const int b = blockIdx.x, tid = threadIdx.x;
  for (int i = tid; i < 768; i += 128) {
    int L = i >> 8, u = i & 255;
    hs[i] = (float)h1buf[(L * 2 + 1) * 32768 + b * 256 + u];  // final parity = 1 (T even)
  }
  __syncthreads();
  if (tid < NOUT) {
    float acc = fb[tid];
    for (int u = 0; u < 768; ++u) acc += hs[u] * fW[u * NOUT + tid];
    out[b * NOUT + tid] = acc;
  }
}

// =====================================================================
extern "C" void kernel_launch(void* const* d_in, const int* in_sizes, int n_in,
                              void* d_out, int out_size, void* d_ws, size_t ws_size,
                              hipStream_t stream)
{
  (void)in_sizes; (void)n_in; (void)out_size; (void)ws_size;
  char* ws = (char*)d_ws;
  BarT* bars      = (BarT*)ws;                             // 512 B reserved
  bf16* h0buf     = (bf16*)(ws + 512);                     // 3*2*128*256*2 = 393216
  bf16* h1buf     = (bf16*)(ws + 512 + 393216);            // 393216
  bf16* comp_emb  = (bf16*)(ws + 786944);                  // 98304*128*2 = 25165824
  bf16* buff_emb  = (bf16*)(ws + 786944 + 25165824);       // 8192*128*2  = 2097152
  bf16* stack_emb = (bf16*)(ws + 786944 + 25165824 + 2097152); // 6144*128*2 = 1572864

  hipMemsetAsync(ws, 0, 786944, stream);  // barriers + h0/h1 init state

  k_emb<<<1664, 256, 0, stream>>>(
      (const int*)d_in[0], (const int*)d_in[1], (const int*)d_in[2], (const int*)d_in[3],
      (const float*)d_in[13], (const float*)d_in[10], (const float*)d_in[14], (const float*)d_in[15],
      comp_emb, buff_emb);

  k_compose<<<384, 256, 0, stream>>>(
      (const int*)d_in[2], (const int*)d_in[4], (const int*)d_in[5],
      comp_emb, (const float*)d_in[11], (const float*)d_in[16], (const float*)d_in[17],
      stack_emb);

  k_lstm<<<48, 256, 0, stream>>>(
      (const float*)d_in[18], (const float*)d_in[19], (const float*)d_in[20], (const float*)d_in[21],
      (const float*)d_in[22], (const float*)d_in[23], (const float*)d_in[24], (const float*)d_in[25],
      (const float*)d_in[26], (const float*)d_in[27], (const float*)d_in[28], (const float*)d_in[29],
      stack_emb, buff_emb, (const float*)d_in[12], (const int*)d_in[6],
      (const int*)d_in[7], (const int*)d_in[8], (const int*)d_in[9],
      h0buf, h1buf, bars);

  k_final<<<128, 128, 0, stream>>>(h1buf, (const float*)d_in[30], (const float*)d_in[31],
                                   (float*)d_out);
}

// Round 3
// 2109.684 us; speedup vs baseline: 1.1728x; 1.1728x over previous
//
#include <hip/hip_runtime.h>

// ---------------- problem constants ----------------
#define BB    128
#define BUFF  64
#define STK   48
#define NCOMP 8
#define HIST  96
#define WDIM  300
#define POSD  50
#define CAD   50
#define HAD   50
#define FC    128
#define UU    256
#define NOUT  82

typedef __bf16 bf16;
typedef __attribute__((ext_vector_type(8))) __bf16 bf16x8;
typedef __attribute__((ext_vector_type(4))) float   f32x4;

__device__ __forceinline__ float sigf(float x)   { return 1.f / (1.f + __expf(-x)); }
__device__ __forceinline__ float tanhf_(float x) { return 1.f - 2.f / (1.f + __expf(2.f * x)); }

// pack two consecutive fp32 values as two bf16 in one u32
__device__ __forceinline__ unsigned pack2(const float* p) {
  union { unsigned u; bf16 h[2]; } r;
  r.h[0] = (bf16)p[0]; r.h[1] = (bf16)p[1];
  return r.u;
}

__device__ __forceinline__ bf16x8 aload16(const bf16* p) {
  union { unsigned long long q[2]; bf16x8 v; } u;
  u.q[0] = __hip_atomic_load((const unsigned long long*)p,       __ATOMIC_RELAXED, __HIP_MEMORY_SCOPE_AGENT);
  u.q[1] = __hip_atomic_load((const unsigned long long*)(p + 4), __ATOMIC_RELAXED, __HIP_MEMORY_SCOPE_AGENT);
  return u.v;
}

// =====================================================================
// Kernel 1: embedding MLP.  rows 0..98303 = comp, 98304..106495 = buff.
// out = relu(concat(w_emb[word](300), p_emb[pos](50)) @ emb_W(350x128) + b)
// =====================================================================
__global__ __launch_bounds__(256) void k_emb(
    const int* bw, const int* bp, const int* cw, const int* cp,
    const float* w_emb, const float* p_emb, const float* embW, const float* embB,
    bf16* comp_emb, bf16* buff_emb)
{
  __shared__ __align__(16) char sm[138752];
  bf16*  A  = (bf16*)sm;                    // [64][360]
  bf16*  Wt = (bf16*)(sm + 46080);          // [128][360] (transposed: [n][k])
  float* sb = (float*)(sm + 46080 + 92160); // [128]

  const int tid = threadIdx.x;
  const int r0  = blockIdx.x * 64;

  // stage A rows (word||pos||0), converting fp32 -> bf16, 2 per u32
  for (int i = tid; i < 64 * 176; i += 256) {
    int m = i / 176, c2 = i % 176, e0 = 2 * c2;
    int r = r0 + m;
    unsigned v;
    if (e0 < 300) {
      int word = (r < 98304) ? cw[r] : bw[r - 98304];
      v = pack2(w_emb + word * 300 + e0);
    } else if (e0 < 350) {
      int pos = (r < 98304) ? cp[r] : bp[r - 98304];
      v = pack2(p_emb + pos * 50 + (e0 - 300));
    } else v = 0u;
    *(unsigned*)(A + m * 360 + e0) = v;
  }
  // stage W transposed (fp32 -> bf16)
  for (int i = tid; i < 350 * 128; i += 256) {
    int k = i >> 7, n = i & 127;
    Wt[n * 360 + k] = (bf16)embW[i];
  }
  // zero k=350,351 in Wt
  { int i = tid; if (i < 256) { int n = i >> 1; Wt[n * 360 + 350 + (i & 1)] = (bf16)0.f; } }
  if (tid < 128) sb[tid] = embB[tid];
  __syncthreads();

  const int wv = tid >> 6, lane = tid & 63, l15 = lane & 15, quad = lane >> 4;
  f32x4 acc[8];
#pragma unroll
  for (int i = 0; i < 8; ++i) acc[i] = (f32x4){0.f, 0.f, 0.f, 0.f};

  const bf16* Arow = A + (wv * 16 + l15) * 360;
  for (int ks = 0; ks < 11; ++ks) {
    int kq = ks * 32 + quad * 8;
    bf16x8 a = *(const bf16x8*)(Arow + kq);
#pragma unroll
    for (int nt = 0; nt < 8; ++nt) {
      bf16x8 b = *(const bf16x8*)(Wt + (nt * 16 + l15) * 360 + kq);
      acc[nt] = __builtin_amdgcn_mfma_f32_16x16x32_bf16(a, b, acc[nt], 0, 0, 0);
    }
  }
#pragma unroll
  for (int nt = 0; nt < 8; ++nt)
#pragma unroll
    for (int rr = 0; rr < 4; ++rr) {
      int row = wv * 16 + quad * 4 + rr;
      int n   = nt * 16 + l15;
      float z = fmaxf(acc[nt][rr] + sb[n], 0.f);
      int r = r0 + row;
      bf16 o = (bf16)z;
      if (r < 98304) comp_emb[r * 128 + n] = o;
      else           buff_emb[(r - 98304) * 128 + n] = o;
    }
}

// =====================================================================
// Kernel 2: compose.  16 (b,s) pairs per block, 8 sequential steps in LDS.
// =====================================================================
__global__ __launch_bounds__(256) void k_compose(
    const int* cw, const int* caid, const int* calen,
    const bf16* comp_emb, const float* ca_emb, const float* recW, const float* recB,
    bf16* stack_emb)
{
  __shared__ __align__(16) char sm[129344];
  bf16*  Wt   = (bf16*)sm;              // [128][328]
  bf16*  X    = (bf16*)(sm + 83968);    // [16][328]
  bf16*  VALS = (bf16*)(sm + 94464);    // [16][8][128]
  float* recb = (float*)(sm + 127232);  // [128]
  int*   IH   = (int*)(sm + 127744);    // [16][8]
  int*   ID   = (int*)(sm + 128256);
  int*   AN   = (int*)(sm + 128768);
  int*   ALEN = (int*)(sm + 129280);    // [16]

  const int tid = threadIdx.x;
  const int bs0 = blockIdx.x * 16;

  for (int i = tid; i < 306 * 128; i += 256) {
    int k = i >> 7, n = i & 127;
    Wt[n * 328 + k] = (bf16)recW[i];
  }
  for (int i = tid; i < 128 * 22; i += 256) {  // zero pad rows 306..327
    int n = i / 22, k = 306 + i % 22;
    Wt[n * 328 + k] = (bf16)0.f;
  }
  if (tid < 128) recb[tid] = recB[tid];
  if (tid < 16) {
    int bs = bs0 + tid;
    int hid[8], did[8];
#pragma unroll
    for (int m = 0; m < 8; ++m) { hid[m] = cw[bs * 16 + 2 * m]; did[m] = cw[bs * 16 + 2 * m + 1]; }
    for (int n = 0; n < 8; ++n) {
      int ih = -1, idd = -1;
      for (int m = 0; m < n; ++m) { if (hid[m] == hid[n]) ih = m; if (hid[m] == did[n]) idd = m; }
      IH[tid * 8 + n] = ih; ID[tid * 8 + n] = idd; AN[tid * 8 + n] = caid[bs * 8 + n];
    }
    ALEN[tid] = calen[bs];
  }
  __syncthreads();

  const int wv = tid >> 6, lane = tid & 63, l15 = lane & 15, quad = lane >> 4;

  for (int n = 0; n < 8; ++n) {
    // stage X = [head_e(128) | act(50) | dep_e(128) | 0 pad] per pair
    for (int i = tid; i < 16 * 160; i += 256) {
      int p = i / 160, c2 = i % 160, e0 = 2 * c2;
      int bs = bs0 + p;
      unsigned v;
      if (e0 < 128) {
        int ih = IH[p * 8 + n];
        v = (ih >= 0) ? *(const unsigned*)(VALS + (p * 8 + ih) * 128 + e0)
                      : *(const unsigned*)(comp_emb + (bs * 16 + 2 * n) * 128 + e0);
      } else if (e0 < 178) {
        v = pack2(ca_emb + AN[p * 8 + n] * 50 + (e0 - 128));
      } else if (e0 < 306) {
        int e = e0 - 178;
        int idd = ID[p * 8 + n];
        v = (idd >= 0) ? *(const unsigned*)(VALS + (p * 8 + idd) * 128 + e)
                       : *(const unsigned*)(comp_emb + (bs * 16 + 2 * n + 1) * 128 + e);
      } else v = 0u;
      *(unsigned*)(X + p * 328 + e0) = v;
    }
    __syncthreads();

    f32x4 acc[2];
    acc[0] = (f32x4){0.f,0.f,0.f,0.f}; acc[1] = (f32x4){0.f,0.f,0.f,0.f};
    for (int ks = 0; ks < 10; ++ks) {
      int kq = ks * 32 + quad * 8;
      bf16x8 a = *(const bf16x8*)(X + l15 * 328 + kq);
#pragma unroll
      for (int t2 = 0; t2 < 2; ++t2) {
        int nt = 2 * wv + t2;
        bf16x8 b = *(const bf16x8*)(Wt + (nt * 16 + l15) * 328 + kq);
        acc[t2] = __builtin_amdgcn_mfma_f32_16x16x32_bf16(a, b, acc[t2], 0, 0, 0);
      }
    }
    __syncthreads();
#pragma unroll
    for (int t2 = 0; t2 < 2; ++t2) {
      int nt = 2 * wv + t2;
#pragma unroll
      for (int rr = 0; rr < 4; ++rr) {
        int p = quad * 4 + rr;
        int col = nt * 16 + l15;
        VALS[(p * 8 + n) * 128 + col] = (bf16)tanhf_(acc[t2][rr] + recb[col]);
      }
    }
    __syncthreads();
  }

  for (int i = tid; i < 16 * 64; i += 256) {
    int p = i / 64, c2 = i % 64, e0 = 2 * c2;
    int bs = bs0 + p;
    int al = ALEN[p];
    unsigned v = (al == 0) ? *(const unsigned*)(comp_emb + (bs * 16) * 128 + e0)
                           : *(const unsigned*)(VALS + (p * 8 + (al - 1)) * 128 + e0);
    *(unsigned*)(stack_emb + bs * 128 + e0) = v;
  }
}

// =====================================================================
// Kernel 3: persistent 3x 2-layer masked LSTM.
// 48 blocks: L = bx/16; within: layer = (bx%16)/8, uchunk = bx%8
// (32 u-columns of all 4 gates).  Phase p: L0 computes step p, L1 computes
// step p-1 (skewed) -> one inter-block barrier per phase.
// Barrier: monotone relaxed counter, NO acquire/release (agent-scope
// acquire/release emit L2 inv/writeback each phase -> was 128MB FETCH and
// ~17us/phase of refetch latency).  All cross-block h data moves via sc1
// atomics (bypass L2, coherent at MALL); __syncthreads drains vmcnt before
// arrival, giving the ordering for free.
// =====================================================================
struct BarT { int cnt; int pad[31]; };

__global__ __launch_bounds__(256) void k_lstm(
    const float* sW0, const float* sb0, const float* sW1, const float* sb1,
    const float* bW0, const float* bb0, const float* bW1, const float* bb1,
    const float* aW0, const float* ab0, const float* aW1, const float* ab1,
    const bf16* stack_emb, const bf16* buff_emb, const float* hist_tab, const int* hist_id,
    const int* len_s, const int* len_b, const int* len_a,
    bf16* h0buf, bf16* h1buf, BarT* bars)
{
  __shared__ __align__(16) char sm[143872];
  const int tid = threadIdx.x;
  const int bx  = blockIdx.x;
  const int L     = bx >> 4;
  const int rid   = bx & 15;
  const int layer = rid >> 3;
  const int u0    = (rid & 7) * 32;
  const int T     = (L == 0) ? STK : (L == 1) ? BUFF : HIST;
  const int* lenp = (L == 0) ? len_s : (L == 1) ? len_b : len_a;

  const float *W, *bias;
  int K, KP, Kxp;
  if (layer == 0) {
    W = (L == 0) ? sW0 : (L == 1) ? bW0 : aW0;
    bias = (L == 0) ? sb0 : (L == 1) ? bb0 : ab0;
    if (L == 2) { K = 320; KP = 328; Kxp = 64; } else { K = 384; KP = 392; Kxp = 128; }
  } else {
    W = (L == 0) ? sW1 : (L == 1) ? bW1 : aW1;
    bias = (L == 0) ? sb1 : (L == 1) ? bb1 : ab1;
    K = 512; KP = 520; Kxp = 256;
  }
  bf16*  Wt     = (bf16*)sm;                               // [128][KP]
  bf16*  hstage = (bf16*)(sm + 128 * KP * 2);              // [128][36]
  float* sb     = (float*)(sm + 128 * KP * 2 + 9216);      // [128]
  bf16*  Xa     = (bf16*)(sm + 128 * KP * 2 + 9216 + 512); // [128][72] (action L0)

  // stage weight slice, transposed: Wt[cc][kk], cc = gate*32 + within
  for (int i = tid; i < K * 128; i += 256) {
    int kk = i >> 7, cc = i & 127;
    int col = (cc >> 5) * 256 + u0 + (cc & 31);
    bf16 v;
    if (layer == 0 && L == 2) {
      if (kk < 64) v = (kk < 50) ? (bf16)W[kk * 1024 + col] : (bf16)0.f;
      else         v = (bf16)W[(kk - 14) * 1024 + col];
    } else v = (bf16)W[kk * 1024 + col];
    Wt[cc * KP + kk] = v;
  }
  if (tid < 128) { int col = (tid >> 5) * 256 + u0 + (tid & 31); sb[tid] = bias[col]; }

  const int wv = tid >> 6, lane = tid & 63, l15 = lane & 15, quad = lane >> 4;
  int lenr[8];
#pragma unroll
  for (int mt = 0; mt < 2; ++mt)
#pragma unroll
    for (int rr = 0; rr < 4; ++rr)
      lenr[mt * 4 + rr] = lenp[32 * wv + 16 * mt + quad * 4 + rr];

  float cst[16], hst[16];
#pragma unroll
  for (int i = 0; i < 16; ++i) { cst[i] = 0.f; hst[i] = 0.f; }

  BarT* bar = bars + L;
  bf16* h0w = h0buf + L * 2 * 32768;  // [2][128][256]
  bf16* h1w = h1buf + L * 2 * 32768;
  const bf16* xsrc = (L == 0) ? stack_emb : buff_emb;
  const int Tx = (L == 0) ? STK : BUFF;

  __syncthreads();

  for (int p = 0; p <= T; ++p) {
    const bool active = (layer == 0) ? (p < T) : (p >= 1);
    const int  t = (layer == 0) ? p : (p - 1);

    if (L == 2 && layer == 0 && active) {  // stage action x_t (50 -> 64 padded)
      for (int i = tid; i < 128 * 32; i += 256) {
        int row = i >> 5, e0 = 2 * (i & 31);
        unsigned v = 0u;
        if (e0 < 50) { int id = hist_id[row * 96 + t]; v = pack2(hist_tab + id * 50 + e0); }
        *(unsigned*)(Xa + row * 72 + e0) = v;
      }
    }
    __syncthreads();

    if (active) {
      f32x4 acc[2][8];
#pragma unroll
      for (int a1 = 0; a1 < 2; ++a1)
#pragma unroll
        for (int a2 = 0; a2 < 8; ++a2) acc[a1][a2] = (f32x4){0.f, 0.f, 0.f, 0.f};

      const bf16* h0r = h0w + ((p - 1) & 1) * 32768;
      const bf16* h1r = h1w + (p & 1) * 32768;

      for (int ks = 0; ks < K / 32; ++ks) {
        int k0 = ks * 32;
        int kq = k0 + quad * 8;
        bf16x8 a[2];
#pragma unroll
        for (int mt = 0; mt < 2; ++mt) {
          int row = 32 * wv + 16 * mt + l15;
          if (layer == 0) {
            if (k0 < Kxp) {
              if (L == 2) a[mt] = *(const bf16x8*)(Xa + row * 72 + kq);
              else        a[mt] = *(const bf16x8*)(xsrc + (row * Tx + t) * 128 + kq);
            } else a[mt] = aload16(h0r + row * 256 + (kq - Kxp));
          } else {
            if (k0 < 256) a[mt] = aload16(h0r + row * 256 + kq);
            else          a[mt] = aload16(h1r + row * 256 + (kq - 256));
          }
        }
#pragma unroll
        for (int nt = 0; nt < 8; ++nt) {
          bf16x8 b = *(const bf16x8*)(Wt + (nt * 16 + l15) * KP + kq);
          acc[0][nt] = __builtin_amdgcn_mfma_f32_16x16x32_bf16(a[0], b, acc[0][nt], 0, 0, 0);
          acc[1][nt] = __builtin_amdgcn_mfma_f32_16x16x32_bf16(a[1], b, acc[1][nt], 0, 0, 0);
        }
      }
      // gates: nt 0,1 = i ; 2,3 = j ; 4,5 = f ; 6,7 = o
#pragma unroll
      for (int mt = 0; mt < 2; ++mt)
#pragma unroll
        for (int g2 = 0; g2 < 2; ++g2)
#pragma unroll
          for (int rr = 0; rr < 4; ++rr) {
            int row = 32 * wv + 16 * mt + quad * 4 + rr;
            float zi = acc[mt][0 + g2][rr] + sb[(0 + g2) * 16 + l15];
            float zj = acc[mt][2 + g2][rr] + sb[(2 + g2) * 16 + l15];
            float zf = acc[mt][4 + g2][rr] + sb[(4 + g2) * 16 + l15];
            float zo = acc[mt][6 + g2][rr] + sb[(6 + g2) * 16 + l15];
            float ig = sigf(zi), jg = tanhf_(zj), fg = sigf(zf + 1.f), og = sigf(zo);
            int idx = mt * 8 + g2 * 4 + rr;
            float cn = cst[idx] * fg + ig * jg;
            float hn = tanhf_(cn) * og;
            bool mk = (t < lenr[mt * 4 + rr]);
            cst[idx] = mk ? cn : cst[idx];
            hst[idx] = mk ? hn : hst[idx];
            hstage[row * 36 + g2 * 16 + l15] = (bf16)hst[idx];
          }
    }
    __syncthreads();
    if (active) {
      bf16* dst = (layer == 0) ? (h0w + (p & 1) * 32768) : (h1w + ((p - 1) & 1) * 32768);
      for (int i = tid; i < 128 * 8; i += 256) {
        int row = i >> 3, c = i & 7;
        unsigned long long v = *(const unsigned long long*)(hstage + row * 36 + c * 4);
        __hip_atomic_store((unsigned long long*)(dst + row * 256 + u0 + c * 4), v,
                           __ATOMIC_RELAXED, __HIP_MEMORY_SCOPE_AGENT);
      }
    }
    // inter-block barrier: monotone relaxed counter (16 participants/LSTM).
    // __syncthreads (below and in-loop) drains each thread's vmcnt, so all
    // sc1 h-stores are at the coherence point before the arrival add.
    __syncthreads();
    if (tid == 0) {
      __builtin_amdgcn_sched_barrier(0);
      const int target = 16 * (p + 1);
      int prev = __hip_atomic_fetch_add(&bar->cnt, 1, __ATOMIC_RELAXED, __HIP_MEMORY_SCOPE_AGENT);
      if (prev != target - 1) {
        while (__hip_atomic_load(&bar->cnt, __ATOMIC_RELAXED, __HIP_MEMORY_SCOPE_AGENT) < target) { }
      }
      __builtin_amdgcn_sched_barrier(0);
    }
    __syncthreads();
  }
}

// =====================================================================
// Kernel 4: out = concat(h_s,h_b,h_a) @ fW + fb
// =====================================================================
__global__ __launch_bounds__(128) void k_final(
    const bf16* h1buf, const float* fW, const float* fb, float* out)
{
  __shared__ float hs[768];
  const int b = blockIdx.x, tid = threadIdx.x;
  for (int i = tid; i < 768; i += 128) {
    int L = i >> 8, u = i & 255;
    hs[i] = (float)h1buf[(L * 2 + 1) * 32768 + b * 256 + u];  // final parity = 1 (T even)
  }
  __syncthreads();
  if (tid < NOUT) {
    float acc = fb[tid];
    for (int u = 0; u < 768; ++u) acc += hs[u] * fW[u * NOUT + tid];
    out[b * NOUT + tid] = acc;
  }
}

// =====================================================================
extern "C" void kernel_launch(void* const* d_in, const int* in_sizes, int n_in,
                              void* d_out, int out_size, void* d_ws, size_t ws_size,
                              hipStream_t stream)
{
  (void)in_sizes; (void)n_in; (void)out_size; (void)ws_size;
  char* ws = (char*)d_ws;
  BarT* bars      = (BarT*)ws;                             // 512 B reserved
  bf16* h0buf     = (bf16*)(ws + 512);                     // 3*2*128*256*2 = 393216
  bf16* h1buf     = (bf16*)(ws + 512 + 393216);            // 393216
  bf16* comp_emb  = (bf16*)(ws + 786944);                  // 98304*128*2 = 25165824
  bf16* buff_emb  = (bf16*)(ws + 786944 + 25165824);       // 8192*128*2  = 2097152
  bf16* stack_emb = (bf16*)(ws + 786944 + 25165824 + 2097152); // 6144*128*2 = 1572864

  hipMemsetAsync(ws, 0, 786944, stream);  // barriers + h0/h1 init state

  k_emb<<<1664, 256, 0, stream>>>(
      (const int*)d_in[0], (const int*)d_in[1], (const int*)d_in[2], (const int*)d_in[3],
      (const float*)d_in[13], (const float*)d_in[10], (const float*)d_in[14], (const float*)d_in[15],
      comp_emb, buff_emb);

  k_compose<<<384, 256, 0, stream>>>(
      (const int*)d_in[2], (const int*)d_in[4], (const int*)d_in[5],
      comp_emb, (const float*)d_in[11], (const float*)d_in[16], (const float*)d_in[17],
      stack_emb);

  k_lstm<<<48, 256, 0, stream>>>(
      (const float*)d_in[18], (const float*)d_in[19], (const float*)d_in[20], (const float*)d_in[21],
      (const float*)d_in[22], (const float*)d_in[23], (const float*)d_in[24], (const float*)d_in[25],
      (const float*)d_in[26], (const float*)d_in[27], (const float*)d_in[28], (const float*)d_in[29],
      stack_emb, buff_emb, (const float*)d_in[12], (const int*)d_in[6],
      (const int*)d_in[7], (const int*)d_in[8], (const int*)d_in[9],
      h0buf, h1buf, bars);

  k_final<<<128, 128, 0, stream>>>(h1buf, (const float*)d_in[30], (const float*)d_in[31],
                                   (float*)d_out);
}